// Round 6
// baseline (213.127 us; speedup 1.0000x reference)
//
#include <hip/hip_runtime.h>
#include <stdint.h>

// ShuffledGroupWhitening on MI355X.
// x: [3*8192, 1024] f32, perms: [3,1024] i32.
// Per (view s, group g): gather 16 permuted cols, center over batch,
// whiten with cov^{-1/2} (Newton-Schulz), scatter back (same col set).
//
// R5 -> R6: stats was stalled 85% with all pipes idle -> in-flight-bytes
// bound (single-depth pipeline: 16 KB of loads per barrier period, vmcnt
// drained at each ds_write). Now depth-2 prefetch: two register sets
// (rrA/rrB, manual unroll-by-2 for static indexing), so two chunks' loads
// are always outstanding and each ds_write waits on loads issued two
// compute-phases earlier. Same in apply. One barrier/chunk (stats),
// hazards fenced by the alternating-parity barriers.

constexpr int D_FEAT  = 1024;
constexpr int NGROUP  = 64;
constexpr int GD      = 16;     // group dim
constexpr int NB      = 8192;   // rows per view
constexpr int NVIEW   = 3;

constexpr int P1      = 256;    // stats blocks per view (768 total = 3/CU)
constexpr int RPP1    = NB / P1;        // 32 rows per stats block
constexpr int C1      = 4;      // chunk rows (stats)
constexpr int RPB3    = 32;     // rows per apply block
constexpr int C3      = 4;      // chunk rows (apply)
constexpr int PSPLIT  = 8;      // reduce split factor

constexpr int SXX_FLOATS  = NGROUP * GD * GD;        // 16384 per view
constexpr int PART_STRIDE = SXX_FLOATS + D_FEAT;     // 17408 per partial
constexpr int ENT         = NVIEW * PART_STRIDE;     // 52224 stat entries

// ws layout (floats) — partials live in d_out, NOT here
constexpr int SXX_OFF = 0;                           // [3][64][16][16]
constexpr int SX_OFF  = NVIEW * SXX_FLOATS;          // 49152: [3][1024]
constexpr int W_OFF   = SX_OFF + NVIEW * D_FEAT;     // 52224: [3][64][16][16]
constexpr int RED_OFF = W_OFF + NVIEW * SXX_FLOATS;  // 101376: [8][52224]
// total ws use = RED_OFF + PSPLIT*ENT = 519168 floats ~ 2.1 MB

// quad broadcast: every lane gets lane ((lane&~3)+B)'s value. Pure VALU DPP.
template <int B>
__device__ __forceinline__ float qbc(float x) {
    return __int_as_float(__builtin_amdgcn_mov_dpp(
        __float_as_int(x), B * 0x55 /*quad_perm[B,B,B,B]*/, 0xF, 0xF, true));
}

// ---------------- Pass 1a: per-block partial Sxx and Sx (no atomics) ----------------
// block: 256 threads; thread = (g = tid>>2, q = tid&3): gathers its own quad
// vq[4] from LDS, rebuilds v[16] via DPP, accumulates acc[i][jj] = sum v[i]*vq[jj].
__global__ __launch_bounds__(256, 3) void k_stats_part(const float* __restrict__ x,
                                                       const int* __restrict__ perms,
                                                       float* __restrict__ part) {
    __shared__ float buf[2][C1][D_FEAT];             // 32 KB double buffer
    const int s   = blockIdx.y;
    const int p   = blockIdx.x;
    const int tid = threadIdx.x;

    // this thread's 4 permuted column indices (coalesced load)
    int pcolq[4];
#pragma unroll
    for (int jj = 0; jj < 4; ++jj) pcolq[jj] = perms[s * D_FEAT + tid * 4 + jj];

    float acc[GD][4];
#pragma unroll
    for (int i = 0; i < GD; ++i)
#pragma unroll
        for (int jj = 0; jj < 4; ++jj) acc[i][jj] = 0.0f;
    float sacc[4] = {0.0f, 0.0f, 0.0f, 0.0f};

    const float* xbase = x + (size_t)(s * NB + p * RPP1) * D_FEAT;
    constexpr int NCH = RPP1 / C1;                   // 8 chunks (even)

    auto loadc = [&](float4* rr, int c) {
        const float* src = xbase + (size_t)c * C1 * D_FEAT;
#pragma unroll
        for (int t = 0; t < C1; ++t)
            rr[t] = *(const float4*)&src[(size_t)t * D_FEAT + tid * 4];
    };
    auto compute = [&](const float (*cb)[D_FEAT]) {
#pragma unroll
        for (int r = 0; r < C1; ++r) {
            float vq[4];
#pragma unroll
            for (int jj = 0; jj < 4; ++jj) vq[jj] = cb[r][pcolq[jj]];
            float v[GD];
#pragma unroll
            for (int jj = 0; jj < 4; ++jj) {
                v[0  + jj] = qbc<0>(vq[jj]);
                v[4  + jj] = qbc<1>(vq[jj]);
                v[8  + jj] = qbc<2>(vq[jj]);
                v[12 + jj] = qbc<3>(vq[jj]);
            }
#pragma unroll
            for (int jj = 0; jj < 4; ++jj) sacc[jj] += vq[jj];
#pragma unroll
            for (int i = 0; i < GD; ++i)
#pragma unroll
                for (int jj = 0; jj < 4; ++jj)
                    acc[i][jj] = fmaf(v[i], vq[jj], acc[i][jj]);
        }
    };

    // depth-2 prologue: chunks 0,1 in flight
    float4 rrA[C1], rrB[C1];
    loadc(rrA, 0);
    loadc(rrB, 1);

    for (int k = 0; k < NCH; k += 2) {
        // even chunk k (parity 0): wait here is for rrA, issued 2 phases ago
#pragma unroll
        for (int t = 0; t < C1; ++t)
            *(float4*)&buf[0][t][tid * 4] = rrA[t];
        __syncthreads();                             // fences write(0,k) / reads(0,k-2)
        if (k + 2 < NCH) loadc(rrA, k + 2);          // refill A: 2 chunks stay in flight
        compute(buf[0]);
        // odd chunk k+1 (parity 1): last readers of buf[1] fenced by barrier above
#pragma unroll
        for (int t = 0; t < C1; ++t)
            *(float4*)&buf[1][t][tid * 4] = rrB[t];
        __syncthreads();
        if (k + 3 < NCH) loadc(rrB, k + 3);
        compute(buf[1]);
    }

    // partial layout: [s*P1+p][ i*1024 + tid*4 + jj ] for Sxx, [16384 + tid*4 + jj] for Sx
    float* dst = part + (size_t)(s * P1 + p) * PART_STRIDE;
#pragma unroll
    for (int i = 0; i < GD; ++i)
        *(float4*)&dst[i * D_FEAT + tid * 4] =
            make_float4(acc[i][0], acc[i][1], acc[i][2], acc[i][3]);
    *(float4*)&dst[SXX_FLOATS + tid * 4] = make_float4(sacc[0], sacc[1], sacc[2], sacc[3]);
}

// ---------------- Pass 1b: reduce partials, stage 1 (P1 -> PSPLIT) ----------------
__global__ __launch_bounds__(256) void k_reduce1(const float* __restrict__ part,
                                                 float* __restrict__ red) {
    const int f = blockIdx.x * 256 + threadIdx.x;
    if (f >= ENT) return;
    const int s = f / PART_STRIDE, ff = f % PART_STRIDE;
    constexpr int PER = P1 / PSPLIT;                 // 32
    const float* src = part + ((size_t)s * P1 + blockIdx.y * PER) * PART_STRIDE + ff;
    float sum = 0.0f;
#pragma unroll 8
    for (int p = 0; p < PER; ++p) sum += src[(size_t)p * PART_STRIDE];
    red[(size_t)blockIdx.y * ENT + f] = sum;
}

// ---------------- Pass 1c: reduce stage 2 (PSPLIT -> 1) + scatter into ws ----------------
__global__ __launch_bounds__(256) void k_reduce2(const float* __restrict__ red,
                                                 float* __restrict__ ws) {
    const int f = blockIdx.x * 256 + threadIdx.x;
    if (f >= ENT) return;
    float sum = 0.0f;
#pragma unroll
    for (int pp = 0; pp < PSPLIT; ++pp) sum += red[(size_t)pp * ENT + f];
    const int s = f / PART_STRIDE, rest = f % PART_STRIDE;
    if (rest < SXX_FLOATS) {
        // rest = i*1024 + g*16 + j
        const int i = rest >> 10;
        const int g = (rest & 1023) >> 4;
        const int j = rest & 15;
        ws[SXX_OFF + (size_t)((s * NGROUP + g) * GD + i) * GD + j] = sum;
    } else {
        ws[SX_OFF + s * D_FEAT + (rest - SXX_FLOATS)] = sum;
    }
}

// ---------------- Pass 2: W = cov^{-1/2} via Newton-Schulz ----------------
// one block per (s,g); thread = (i = tid>>4, j = tid&15) entry of 16x16.
__global__ __launch_bounds__(256) void k_invsqrt(float* __restrict__ ws) {
    __shared__ float Ym[GD][GD];
    __shared__ float Zm[GD][GD];
    __shared__ float Tm[GD][GD];
    const int bx = blockIdx.x;
    const int s = bx / NGROUP, g = bx % NGROUP;
    const int tid = threadIdx.x;
    const int i = tid >> 4, j = tid & 15;
    const float invB = 1.0f / (float)NB;

    const float sxx = ws[SXX_OFF + (size_t)((s * NGROUP + g) * GD + i) * GD + j];
    const float mui = ws[SX_OFF + s * D_FEAT + g * GD + i] * invB;
    const float muj = ws[SX_OFF + s * D_FEAT + g * GD + j] * invB;
    const float a = sxx * invB - mui * muj;   // cov entry

    Ym[i][j] = a;
    __syncthreads();
    float tr = 0.0f;
#pragma unroll
    for (int k = 0; k < GD; ++k) tr += Ym[k][k];
    const float sc = tr * (1.0f / (float)GD);   // ~1.0 for N(0,1) data
    const float inv_sc = 1.0f / sc;
    __syncthreads();                            // all trace reads done
    Ym[i][j] = a * inv_sc;                      // normalized A, eig in ~[0.9,1.1]
    Zm[i][j] = (i == j) ? 1.0f : 0.0f;
    __syncthreads();

    float zn = (i == j) ? 1.0f : 0.0f;
    for (int it = 0; it < 6; ++it) {
        float t = 0.0f;
#pragma unroll
        for (int k = 0; k < GD; ++k) t += Zm[i][k] * Ym[k][j];
        t = ((i == j) ? 1.5f : 0.0f) - 0.5f * t;
        Tm[i][j] = t;
        __syncthreads();
        float yn = 0.0f;
        zn = 0.0f;
#pragma unroll
        for (int k = 0; k < GD; ++k) {
            yn += Ym[i][k] * Tm[k][j];
            zn += Tm[i][k] * Zm[k][j];
        }
        __syncthreads();
        Ym[i][j] = yn;
        Zm[i][j] = zn;
        __syncthreads();
    }
    // W = Z * sc^{-1/2}
    ws[W_OFF + (size_t)((s * NGROUP + g) * GD + i) * GD + j] = zn * rsqrtf(sc);
}

// ---------------- Pass 3: y = (x_gathered - mu) @ W, scattered back ----------------
// block: 256 threads; thread = (g = tid>>2, q = tid&3) owns W[:, q*4..q*4+3] in regs;
// gathers its quad from LDS, rebuilds v[16] via DPP, scatters u[4] to bout.
__global__ __launch_bounds__(256, 3) void k_apply(const float* __restrict__ x,
                                                  const int* __restrict__ perms,
                                                  const float* __restrict__ ws,
                                                  float* __restrict__ out) {
    __shared__ float bin[2][C3][D_FEAT];             // 32 KB double-buffered input
    __shared__ float bout[C3][D_FEAT];               // 16 KB output staging
    const int s   = blockIdx.y;
    const int rb  = blockIdx.x;
    const int tid = threadIdx.x;
    const int g   = tid >> 2;
    const int q   = tid & 3;
    const float invB = 1.0f / (float)NB;

    int pcolq[4];
#pragma unroll
    for (int jj = 0; jj < 4; ++jj) pcolq[jj] = perms[s * D_FEAT + tid * 4 + jj];

    // W columns for this thread: w[e][ii] = W[s,g][e][q*4+ii]
    const float* Wp = ws + W_OFF + (size_t)(s * NGROUP + g) * GD * GD;
    float w[GD][4];
#pragma unroll
    for (int e = 0; e < GD; ++e) {
        float4 t4 = *(const float4*)&Wp[e * GD + q * 4];
        w[e][0] = t4.x; w[e][1] = t4.y; w[e][2] = t4.z; w[e][3] = t4.w;
    }
    // bias[ii] = sum_e mu[e] * w[e][ii]  (fold centering into the GEMV)
    float bias[4] = {0.0f, 0.0f, 0.0f, 0.0f};
#pragma unroll
    for (int e = 0; e < GD; ++e) {
        const float mu = ws[SX_OFF + s * D_FEAT + g * GD + e] * invB;
#pragma unroll
        for (int ii = 0; ii < 4; ++ii) bias[ii] += mu * w[e][ii];
    }

    const float* xbase = x + (size_t)(s * NB + rb * RPB3) * D_FEAT;
    float* obase = out + (size_t)(s * NB + rb * RPB3) * D_FEAT;
    constexpr int NCH = RPB3 / C3;                   // 8 chunks (even)

    auto loadc = [&](float4* rr, int c) {
        const float* src = xbase + (size_t)c * C3 * D_FEAT;
#pragma unroll
        for (int t = 0; t < C3; ++t)
            rr[t] = *(const float4*)&src[(size_t)t * D_FEAT + tid * 4];
    };
    auto compute = [&](const float (*cb)[D_FEAT]) {
#pragma unroll
        for (int r = 0; r < C3; ++r) {
            float vq[4];
#pragma unroll
            for (int jj = 0; jj < 4; ++jj) vq[jj] = cb[r][pcolq[jj]];
            float v[GD];
#pragma unroll
            for (int jj = 0; jj < 4; ++jj) {
                v[0  + jj] = qbc<0>(vq[jj]);
                v[4  + jj] = qbc<1>(vq[jj]);
                v[8  + jj] = qbc<2>(vq[jj]);
                v[12 + jj] = qbc<3>(vq[jj]);
            }
            float u[4] = {-bias[0], -bias[1], -bias[2], -bias[3]};
#pragma unroll
            for (int e = 0; e < GD; ++e)
#pragma unroll
                for (int ii = 0; ii < 4; ++ii) u[ii] = fmaf(v[e], w[e][ii], u[ii]);
#pragma unroll
            for (int ii = 0; ii < 4; ++ii) bout[r][pcolq[ii]] = u[ii];
        }
    };
    auto storec = [&](int c) {
        float* ob = obase + (size_t)c * C3 * D_FEAT;
#pragma unroll
        for (int t = 0; t < C3; ++t)
            *(float4*)&ob[(size_t)t * D_FEAT + tid * 4] =
                *(const float4*)&bout[t][tid * 4];
    };

    float4 rrA[C3], rrB[C3];
    loadc(rrA, 0);
    loadc(rrB, 1);

    for (int k = 0; k < NCH; k += 2) {
        // even chunk k
#pragma unroll
        for (int t = 0; t < C3; ++t)
            *(float4*)&bin[0][t][tid * 4] = rrA[t];
        __syncthreads();                             // bin[0] visible; bout(k-1) stores done
        if (k + 2 < NCH) loadc(rrA, k + 2);
        compute(bin[0]);
        __syncthreads();                             // bout complete
        storec(k);
        // odd chunk k+1
#pragma unroll
        for (int t = 0; t < C3; ++t)
            *(float4*)&bin[1][t][tid * 4] = rrB[t];
        __syncthreads();
        if (k + 3 < NCH) loadc(rrB, k + 3);
        compute(bin[1]);
        __syncthreads();
        storec(k + 1);
    }
}

extern "C" void kernel_launch(void* const* d_in, const int* in_sizes, int n_in,
                              void* d_out, int out_size, void* d_ws, size_t ws_size,
                              hipStream_t stream) {
    const float* x     = (const float*)d_in[0];
    const int*   perms = (const int*)d_in[1];
    float* out = (float*)d_out;
    float* ws  = (float*)d_ws;

    // Partials (3*256*17408 floats = 53.5 MB) live in d_out: it is 100 MB and
    // k_apply fully overwrites every element afterwards. ws only needs 2.1 MB.
    float* part = out;

    dim3 g1(P1, NVIEW);                              // 768 blocks = 3/CU
    k_stats_part<<<g1, 256, 0, stream>>>(x, perms, part);

    dim3 gr1((ENT + 255) / 256, PSPLIT);             // (204, 8)
    k_reduce1<<<gr1, 256, 0, stream>>>(part, ws + RED_OFF);
    k_reduce2<<<(ENT + 255) / 256, 256, 0, stream>>>(ws + RED_OFF, ws);

    k_invsqrt<<<NVIEW * NGROUP, 256, 0, stream>>>(ws);

    dim3 g3(NB / RPB3, NVIEW);                       // 768 blocks = 3/CU
    k_apply<<<g3, 256, 0, stream>>>(x, perms, ws, out);
}

// Round 7
// 198.597 us; speedup vs baseline: 1.0732x; 1.0732x over previous
//
#include <hip/hip_runtime.h>
#include <stdint.h>

// ShuffledGroupWhitening on MI355X.
// x: [3*8192, 1024] f32, perms: [3,1024] i32.
// Per (view s, group g): gather 16 permuted cols, center over batch,
// whiten with cov^{-1/2} (Newton-Schulz), scatter back (same col set).
//
// R6 -> R7: R6's lambdas took float4* params -> rr arrays went to SCRATCH
// (+250 MB FETCH/WRITE, stats 59->145 us). Same depth-2 pipeline, but coded
// like R5 (constant-indexed arrays in unrolled loops, macro-expanded inline,
// no lambdas/pointers) so the arrays stay in VGPRs.

constexpr int D_FEAT  = 1024;
constexpr int NGROUP  = 64;
constexpr int GD      = 16;     // group dim
constexpr int NB      = 8192;   // rows per view
constexpr int NVIEW   = 3;

constexpr int P1      = 256;    // stats blocks per view (768 total = 3/CU)
constexpr int RPP1    = NB / P1;        // 32 rows per stats block
constexpr int C1      = 4;      // chunk rows (stats)
constexpr int RPB3    = 32;     // rows per apply block
constexpr int C3      = 4;      // chunk rows (apply)
constexpr int PSPLIT  = 8;      // reduce split factor

constexpr int SXX_FLOATS  = NGROUP * GD * GD;        // 16384 per view
constexpr int PART_STRIDE = SXX_FLOATS + D_FEAT;     // 17408 per partial
constexpr int ENT         = NVIEW * PART_STRIDE;     // 52224 stat entries

// ws layout (floats) — partials live in d_out, NOT here
constexpr int SXX_OFF = 0;                           // [3][64][16][16]
constexpr int SX_OFF  = NVIEW * SXX_FLOATS;          // 49152: [3][1024]
constexpr int W_OFF   = SX_OFF + NVIEW * D_FEAT;     // 52224: [3][64][16][16]
constexpr int RED_OFF = W_OFF + NVIEW * SXX_FLOATS;  // 101376: [8][52224]
// total ws use = RED_OFF + PSPLIT*ENT = 519168 floats ~ 2.1 MB

// quad broadcast: every lane gets lane ((lane&~3)+B)'s value. Pure VALU DPP.
template <int B>
__device__ __forceinline__ float qbc(float x) {
    return __int_as_float(__builtin_amdgcn_mov_dpp(
        __float_as_int(x), B * 0x55 /*quad_perm[B,B,B,B]*/, 0xF, 0xF, true));
}

// ---------------- Pass 1a: per-block partial Sxx and Sx (no atomics) ----------------
// block: 256 threads; thread = (g = tid>>2, q = tid&3): gathers its own quad
// vq[4] from LDS, rebuilds v[16] via DPP, accumulates acc[i][jj] = sum v[i]*vq[jj].
__global__ __launch_bounds__(256, 3) void k_stats_part(const float* __restrict__ x,
                                                       const int* __restrict__ perms,
                                                       float* __restrict__ part) {
    __shared__ float buf[2][C1][D_FEAT];             // 32 KB double buffer
    const int s   = blockIdx.y;
    const int p   = blockIdx.x;
    const int tid = threadIdx.x;

    // this thread's 4 permuted column indices (coalesced load)
    int pcolq[4];
#pragma unroll
    for (int jj = 0; jj < 4; ++jj) pcolq[jj] = perms[s * D_FEAT + tid * 4 + jj];

    float acc[GD][4];
#pragma unroll
    for (int i = 0; i < GD; ++i)
#pragma unroll
        for (int jj = 0; jj < 4; ++jj) acc[i][jj] = 0.0f;
    float sacc[4] = {0.0f, 0.0f, 0.0f, 0.0f};

    const float* xbase = x + (size_t)(s * NB + p * RPP1) * D_FEAT;
    constexpr int NCH = RPP1 / C1;                   // 8 chunks (even)

    float4 rrA[C1], rrB[C1];

// load chunk (c) into register set RR — constant-indexed, stays in VGPRs
#define S_LOAD(RR, c)                                                          \
    {                                                                          \
        const float* nx_ = xbase + (size_t)(c) * C1 * D_FEAT + tid * 4;        \
        _Pragma("unroll")                                                      \
        for (int t = 0; t < C1; ++t)                                           \
            RR[t] = *(const float4*)&nx_[(size_t)t * D_FEAT];                  \
    }
// stage register set RR into LDS parity P
#define S_STAGE(RR, P)                                                         \
    {                                                                          \
        _Pragma("unroll")                                                      \
        for (int t = 0; t < C1; ++t)                                           \
            *(float4*)&buf[P][t][tid * 4] = RR[t];                             \
    }
// consume LDS parity P into accumulators
#define S_COMPUTE(P)                                                           \
    {                                                                          \
        _Pragma("unroll")                                                      \
        for (int r = 0; r < C1; ++r) {                                         \
            float vq[4];                                                       \
            _Pragma("unroll")                                                  \
            for (int jj = 0; jj < 4; ++jj) vq[jj] = buf[P][r][pcolq[jj]];      \
            float v[GD];                                                       \
            _Pragma("unroll")                                                  \
            for (int jj = 0; jj < 4; ++jj) {                                   \
                v[0  + jj] = qbc<0>(vq[jj]);                                   \
                v[4  + jj] = qbc<1>(vq[jj]);                                   \
                v[8  + jj] = qbc<2>(vq[jj]);                                   \
                v[12 + jj] = qbc<3>(vq[jj]);                                   \
            }                                                                  \
            _Pragma("unroll")                                                  \
            for (int jj = 0; jj < 4; ++jj) sacc[jj] += vq[jj];                 \
            _Pragma("unroll")                                                  \
            for (int i = 0; i < GD; ++i)                                       \
                _Pragma("unroll")                                              \
                for (int jj = 0; jj < 4; ++jj)                                 \
                    acc[i][jj] = fmaf(v[i], vq[jj], acc[i][jj]);               \
        }                                                                      \
    }

    // depth-2 prologue: chunks 0,1 in flight
    S_LOAD(rrA, 0)
    S_LOAD(rrB, 1)

    for (int k = 0; k < NCH; k += 2) {
        // even chunk k (parity 0): ds_write waits on rrA, issued 2 phases ago
        S_STAGE(rrA, 0)
        __syncthreads();             // fences write(0,k) vs reads(0,k-2)
        if (k + 2 < NCH) S_LOAD(rrA, k + 2)          // keep 2 chunks in flight
        S_COMPUTE(0)
        // odd chunk k+1 (parity 1): readers of buf[1] (k-1) fenced by barrier above
        S_STAGE(rrB, 1)
        __syncthreads();
        if (k + 3 < NCH) S_LOAD(rrB, k + 3)
        S_COMPUTE(1)
    }
#undef S_LOAD
#undef S_STAGE
#undef S_COMPUTE

    // partial layout: [s*P1+p][ i*1024 + tid*4 + jj ] for Sxx, [16384 + tid*4 + jj] for Sx
    float* dst = part + (size_t)(s * P1 + p) * PART_STRIDE;
#pragma unroll
    for (int i = 0; i < GD; ++i)
        *(float4*)&dst[i * D_FEAT + tid * 4] =
            make_float4(acc[i][0], acc[i][1], acc[i][2], acc[i][3]);
    *(float4*)&dst[SXX_FLOATS + tid * 4] = make_float4(sacc[0], sacc[1], sacc[2], sacc[3]);
}

// ---------------- Pass 1b: reduce partials, stage 1 (P1 -> PSPLIT) ----------------
__global__ __launch_bounds__(256) void k_reduce1(const float* __restrict__ part,
                                                 float* __restrict__ red) {
    const int f = blockIdx.x * 256 + threadIdx.x;
    if (f >= ENT) return;
    const int s = f / PART_STRIDE, ff = f % PART_STRIDE;
    constexpr int PER = P1 / PSPLIT;                 // 32
    const float* src = part + ((size_t)s * P1 + blockIdx.y * PER) * PART_STRIDE + ff;
    float sum = 0.0f;
#pragma unroll 8
    for (int p = 0; p < PER; ++p) sum += src[(size_t)p * PART_STRIDE];
    red[(size_t)blockIdx.y * ENT + f] = sum;
}

// ---------------- Pass 1c: reduce stage 2 (PSPLIT -> 1) + scatter into ws ----------------
__global__ __launch_bounds__(256) void k_reduce2(const float* __restrict__ red,
                                                 float* __restrict__ ws) {
    const int f = blockIdx.x * 256 + threadIdx.x;
    if (f >= ENT) return;
    float sum = 0.0f;
#pragma unroll
    for (int pp = 0; pp < PSPLIT; ++pp) sum += red[(size_t)pp * ENT + f];
    const int s = f / PART_STRIDE, rest = f % PART_STRIDE;
    if (rest < SXX_FLOATS) {
        // rest = i*1024 + g*16 + j
        const int i = rest >> 10;
        const int g = (rest & 1023) >> 4;
        const int j = rest & 15;
        ws[SXX_OFF + (size_t)((s * NGROUP + g) * GD + i) * GD + j] = sum;
    } else {
        ws[SX_OFF + s * D_FEAT + (rest - SXX_FLOATS)] = sum;
    }
}

// ---------------- Pass 2: W = cov^{-1/2} via Newton-Schulz ----------------
// one block per (s,g); thread = (i = tid>>4, j = tid&15) entry of 16x16.
__global__ __launch_bounds__(256) void k_invsqrt(float* __restrict__ ws) {
    __shared__ float Ym[GD][GD];
    __shared__ float Zm[GD][GD];
    __shared__ float Tm[GD][GD];
    const int bx = blockIdx.x;
    const int s = bx / NGROUP, g = bx % NGROUP;
    const int tid = threadIdx.x;
    const int i = tid >> 4, j = tid & 15;
    const float invB = 1.0f / (float)NB;

    const float sxx = ws[SXX_OFF + (size_t)((s * NGROUP + g) * GD + i) * GD + j];
    const float mui = ws[SX_OFF + s * D_FEAT + g * GD + i] * invB;
    const float muj = ws[SX_OFF + s * D_FEAT + g * GD + j] * invB;
    const float a = sxx * invB - mui * muj;   // cov entry

    Ym[i][j] = a;
    __syncthreads();
    float tr = 0.0f;
#pragma unroll
    for (int k = 0; k < GD; ++k) tr += Ym[k][k];
    const float sc = tr * (1.0f / (float)GD);   // ~1.0 for N(0,1) data
    const float inv_sc = 1.0f / sc;
    __syncthreads();                            // all trace reads done
    Ym[i][j] = a * inv_sc;                      // normalized A, eig in ~[0.9,1.1]
    Zm[i][j] = (i == j) ? 1.0f : 0.0f;
    __syncthreads();

    float zn = (i == j) ? 1.0f : 0.0f;
    for (int it = 0; it < 6; ++it) {
        float t = 0.0f;
#pragma unroll
        for (int k = 0; k < GD; ++k) t += Zm[i][k] * Ym[k][j];
        t = ((i == j) ? 1.5f : 0.0f) - 0.5f * t;
        Tm[i][j] = t;
        __syncthreads();
        float yn = 0.0f;
        zn = 0.0f;
#pragma unroll
        for (int k = 0; k < GD; ++k) {
            yn += Ym[i][k] * Tm[k][j];
            zn += Tm[i][k] * Zm[k][j];
        }
        __syncthreads();
        Ym[i][j] = yn;
        Zm[i][j] = zn;
        __syncthreads();
    }
    // W = Z * sc^{-1/2}
    ws[W_OFF + (size_t)((s * NGROUP + g) * GD + i) * GD + j] = zn * rsqrtf(sc);
}

// ---------------- Pass 3: y = (x_gathered - mu) @ W, scattered back ----------------
// block: 256 threads; thread = (g = tid>>2, q = tid&3) owns W[:, q*4..q*4+3] in regs;
// gathers its quad from LDS, rebuilds v[16] via DPP, scatters u[4] to bout.
__global__ __launch_bounds__(256, 3) void k_apply(const float* __restrict__ x,
                                                  const int* __restrict__ perms,
                                                  const float* __restrict__ ws,
                                                  float* __restrict__ out) {
    __shared__ float bin[2][C3][D_FEAT];             // 32 KB double-buffered input
    __shared__ float bout[C3][D_FEAT];               // 16 KB output staging
    const int s   = blockIdx.y;
    const int rb  = blockIdx.x;
    const int tid = threadIdx.x;
    const int g   = tid >> 2;
    const int q   = tid & 3;
    const float invB = 1.0f / (float)NB;

    int pcolq[4];
#pragma unroll
    for (int jj = 0; jj < 4; ++jj) pcolq[jj] = perms[s * D_FEAT + tid * 4 + jj];

    // W columns for this thread: w[e][ii] = W[s,g][e][q*4+ii]
    const float* Wp = ws + W_OFF + (size_t)(s * NGROUP + g) * GD * GD;
    float w[GD][4];
#pragma unroll
    for (int e = 0; e < GD; ++e) {
        float4 t4 = *(const float4*)&Wp[e * GD + q * 4];
        w[e][0] = t4.x; w[e][1] = t4.y; w[e][2] = t4.z; w[e][3] = t4.w;
    }
    // bias[ii] = sum_e mu[e] * w[e][ii]  (fold centering into the GEMV)
    float bias[4] = {0.0f, 0.0f, 0.0f, 0.0f};
#pragma unroll
    for (int e = 0; e < GD; ++e) {
        const float mu = ws[SX_OFF + s * D_FEAT + g * GD + e] * invB;
#pragma unroll
        for (int ii = 0; ii < 4; ++ii) bias[ii] += mu * w[e][ii];
    }

    const float* xbase = x + (size_t)(s * NB + rb * RPB3) * D_FEAT;
    float* obase = out + (size_t)(s * NB + rb * RPB3) * D_FEAT;
    constexpr int NCH = RPB3 / C3;                   // 8 chunks (even)

    float4 rrA[C3], rrB[C3];

#define A_LOAD(RR, c)                                                          \
    {                                                                          \
        const float* nx_ = xbase + (size_t)(c) * C3 * D_FEAT + tid * 4;        \
        _Pragma("unroll")                                                      \
        for (int t = 0; t < C3; ++t)                                           \
            RR[t] = *(const float4*)&nx_[(size_t)t * D_FEAT];                  \
    }
#define A_STAGE(RR, P)                                                         \
    {                                                                          \
        _Pragma("unroll")                                                      \
        for (int t = 0; t < C3; ++t)                                           \
            *(float4*)&bin[P][t][tid * 4] = RR[t];                             \
    }
#define A_COMPUTE(P)                                                           \
    {                                                                          \
        _Pragma("unroll")                                                      \
        for (int r = 0; r < C3; ++r) {                                         \
            float vq[4];                                                       \
            _Pragma("unroll")                                                  \
            for (int jj = 0; jj < 4; ++jj) vq[jj] = bin[P][r][pcolq[jj]];      \
            float v[GD];                                                       \
            _Pragma("unroll")                                                  \
            for (int jj = 0; jj < 4; ++jj) {                                   \
                v[0  + jj] = qbc<0>(vq[jj]);                                   \
                v[4  + jj] = qbc<1>(vq[jj]);                                   \
                v[8  + jj] = qbc<2>(vq[jj]);                                   \
                v[12 + jj] = qbc<3>(vq[jj]);                                   \
            }                                                                  \
            float u[4] = {-bias[0], -bias[1], -bias[2], -bias[3]};             \
            _Pragma("unroll")                                                  \
            for (int e = 0; e < GD; ++e)                                       \
                _Pragma("unroll")                                              \
                for (int ii = 0; ii < 4; ++ii)                                 \
                    u[ii] = fmaf(v[e], w[e][ii], u[ii]);                       \
            _Pragma("unroll")                                                  \
            for (int ii = 0; ii < 4; ++ii) bout[r][pcolq[ii]] = u[ii];         \
        }                                                                      \
    }
#define A_STORE(c)                                                             \
    {                                                                          \
        float* ob_ = obase + (size_t)(c) * C3 * D_FEAT + tid * 4;              \
        _Pragma("unroll")                                                      \
        for (int t = 0; t < C3; ++t)                                           \
            *(float4*)&ob_[(size_t)t * D_FEAT] =                               \
                *(const float4*)&bout[t][tid * 4];                             \
    }

    A_LOAD(rrA, 0)
    A_LOAD(rrB, 1)

    for (int k = 0; k < NCH; k += 2) {
        // even chunk k
        A_STAGE(rrA, 0)
        __syncthreads();             // bin[0] visible; bout(k-1) LDS-reads done
        if (k + 2 < NCH) A_LOAD(rrA, k + 2)
        A_COMPUTE(0)
        __syncthreads();             // bout complete
        A_STORE(k)
        // odd chunk k+1
        A_STAGE(rrB, 1)
        __syncthreads();
        if (k + 3 < NCH) A_LOAD(rrB, k + 3)
        A_COMPUTE(1)
        __syncthreads();
        A_STORE(k + 1)
    }
#undef A_LOAD
#undef A_STAGE
#undef A_COMPUTE
#undef A_STORE
}

extern "C" void kernel_launch(void* const* d_in, const int* in_sizes, int n_in,
                              void* d_out, int out_size, void* d_ws, size_t ws_size,
                              hipStream_t stream) {
    const float* x     = (const float*)d_in[0];
    const int*   perms = (const int*)d_in[1];
    float* out = (float*)d_out;
    float* ws  = (float*)d_ws;

    // Partials (3*256*17408 floats = 53.5 MB) live in d_out: it is 100 MB and
    // k_apply fully overwrites every element afterwards. ws only needs 2.1 MB.
    float* part = out;

    dim3 g1(P1, NVIEW);                              // 768 blocks = 3/CU
    k_stats_part<<<g1, 256, 0, stream>>>(x, perms, part);

    dim3 gr1((ENT + 255) / 256, PSPLIT);             // (204, 8)
    k_reduce1<<<gr1, 256, 0, stream>>>(part, ws + RED_OFF);
    k_reduce2<<<(ENT + 255) / 256, 256, 0, stream>>>(ws + RED_OFF, ws);

    k_invsqrt<<<NVIEW * NGROUP, 256, 0, stream>>>(ws);

    dim3 g3(NB / RPB3, NVIEW);                       // 768 blocks = 3/CU
    k_apply<<<g3, 256, 0, stream>>>(x, perms, ws, out);
}

// Round 8
// 102.873 us; speedup vs baseline: 2.0718x; 1.9305x over previous
//
#include <hip/hip_runtime.h>
#include <stdint.h>

// ShuffledGroupWhitening on MI355X.
// x: [3*8192, 1024] f32, perms: [3,1024] i32.
// Per (view s, group g): gather 16 permuted cols, center over batch,
// whiten with cov^{-1/2} (Newton-Schulz), scatter back (same col set).
//
// R7 -> R8: depth-2 LDS pipeline was the regression in BOTH codings
// (lambda and macro) -> structure itself amplified traffic (+250 MB).
// Stats now skips LDS entirely: each thread gathers its own 4 permuted
// columns straight from global (block reads whole rows, so L2 absorbs the
// line-granularity overlap; net HBM unchanged), DPP rebuilds the 16-vector.
// No barriers, no ds_write -> latency hidden by TLP + unrolled loads.
// apply/reduce/invsqrt are the proven R5 versions, unchanged.

constexpr int D_FEAT  = 1024;
constexpr int NGROUP  = 64;
constexpr int GD      = 16;     // group dim
constexpr int NB      = 8192;   // rows per view
constexpr int NVIEW   = 3;

constexpr int P1      = 256;    // stats blocks per view (768 total = 3/CU)
constexpr int RPP1    = NB / P1;        // 32 rows per stats block
constexpr int RPB3    = 32;     // rows per apply block
constexpr int C3      = 4;      // chunk rows (apply)
constexpr int PSPLIT  = 8;      // reduce split factor

constexpr int SXX_FLOATS  = NGROUP * GD * GD;        // 16384 per view
constexpr int PART_STRIDE = SXX_FLOATS + D_FEAT;     // 17408 per partial
constexpr int ENT         = NVIEW * PART_STRIDE;     // 52224 stat entries

// ws layout (floats) — partials live in d_out, NOT here
constexpr int SXX_OFF = 0;                           // [3][64][16][16]
constexpr int SX_OFF  = NVIEW * SXX_FLOATS;          // 49152: [3][1024]
constexpr int W_OFF   = SX_OFF + NVIEW * D_FEAT;     // 52224: [3][64][16][16]
constexpr int RED_OFF = W_OFF + NVIEW * SXX_FLOATS;  // 101376: [8][52224]
// total ws use = RED_OFF + PSPLIT*ENT = 519168 floats ~ 2.1 MB

// quad broadcast: every lane gets lane ((lane&~3)+B)'s value. Pure VALU DPP.
template <int B>
__device__ __forceinline__ float qbc(float x) {
    return __int_as_float(__builtin_amdgcn_mov_dpp(
        __float_as_int(x), B * 0x55 /*quad_perm[B,B,B,B]*/, 0xF, 0xF, true));
}

// ---------------- Pass 1a: per-block partial Sxx and Sx (no LDS, no barriers) ------
// block: 256 threads; thread = (g = tid>>2, q = tid&3): gathers its own quad
// vq[4] DIRECTLY from global (block covers whole rows -> L2 absorbs overlap),
// rebuilds v[16] via DPP, accumulates acc[i][jj] = sum v[i]*vq[jj].
__global__ __launch_bounds__(256, 3) void k_stats_gather(const float* __restrict__ x,
                                                         const int* __restrict__ perms,
                                                         float* __restrict__ part) {
    const int s   = blockIdx.y;
    const int p   = blockIdx.x;
    const int tid = threadIdx.x;

    // this thread's 4 permuted column indices (coalesced load)
    int pcolq[4];
#pragma unroll
    for (int jj = 0; jj < 4; ++jj) pcolq[jj] = perms[s * D_FEAT + tid * 4 + jj];

    float acc[GD][4];
#pragma unroll
    for (int i = 0; i < GD; ++i)
#pragma unroll
        for (int jj = 0; jj < 4; ++jj) acc[i][jj] = 0.0f;
    float sacc[4] = {0.0f, 0.0f, 0.0f, 0.0f};

    const float* xbase = x + (size_t)(s * NB + p * RPP1) * D_FEAT;

// accumulate one row given its 4 gathered quad values
#define ROW_ACC(Q0, Q1, Q2, Q3)                                                \
    {                                                                          \
        float vq_[4] = {Q0, Q1, Q2, Q3};                                       \
        float v_[GD];                                                          \
        _Pragma("unroll")                                                      \
        for (int jj = 0; jj < 4; ++jj) {                                       \
            v_[0  + jj] = qbc<0>(vq_[jj]);                                     \
            v_[4  + jj] = qbc<1>(vq_[jj]);                                     \
            v_[8  + jj] = qbc<2>(vq_[jj]);                                     \
            v_[12 + jj] = qbc<3>(vq_[jj]);                                     \
        }                                                                      \
        _Pragma("unroll")                                                      \
        for (int jj = 0; jj < 4; ++jj) sacc[jj] += vq_[jj];                    \
        _Pragma("unroll")                                                      \
        for (int i = 0; i < GD; ++i)                                           \
            _Pragma("unroll")                                                  \
            for (int jj = 0; jj < 4; ++jj)                                     \
                acc[i][jj] = fmaf(v_[i], vq_[jj], acc[i][jj]);                 \
    }

    // 2 rows per iteration: 8 independent dword gathers issued back-to-back
    // (no barriers anywhere -> they all stay in flight under the compute).
    for (int r = 0; r < RPP1; r += 2) {
        const float* ra = xbase + (size_t)r * D_FEAT;
        const float* rb = ra + D_FEAT;
        const float a0 = ra[pcolq[0]], a1 = ra[pcolq[1]],
                    a2 = ra[pcolq[2]], a3 = ra[pcolq[3]];
        const float b0 = rb[pcolq[0]], b1 = rb[pcolq[1]],
                    b2 = rb[pcolq[2]], b3 = rb[pcolq[3]];
        ROW_ACC(a0, a1, a2, a3)
        ROW_ACC(b0, b1, b2, b3)
    }
#undef ROW_ACC

    // partial layout: [s*P1+p][ i*1024 + tid*4 + jj ] for Sxx, [16384 + tid*4 + jj] for Sx
    float* dst = part + (size_t)(s * P1 + p) * PART_STRIDE;
#pragma unroll
    for (int i = 0; i < GD; ++i)
        *(float4*)&dst[i * D_FEAT + tid * 4] =
            make_float4(acc[i][0], acc[i][1], acc[i][2], acc[i][3]);
    *(float4*)&dst[SXX_FLOATS + tid * 4] = make_float4(sacc[0], sacc[1], sacc[2], sacc[3]);
}

// ---------------- Pass 1b: reduce partials, stage 1 (P1 -> PSPLIT) ----------------
__global__ __launch_bounds__(256) void k_reduce1(const float* __restrict__ part,
                                                 float* __restrict__ red) {
    const int f = blockIdx.x * 256 + threadIdx.x;
    if (f >= ENT) return;
    const int s = f / PART_STRIDE, ff = f % PART_STRIDE;
    constexpr int PER = P1 / PSPLIT;                 // 32
    const float* src = part + ((size_t)s * P1 + blockIdx.y * PER) * PART_STRIDE + ff;
    float sum = 0.0f;
#pragma unroll 8
    for (int p = 0; p < PER; ++p) sum += src[(size_t)p * PART_STRIDE];
    red[(size_t)blockIdx.y * ENT + f] = sum;
}

// ---------------- Pass 1c: reduce stage 2 (PSPLIT -> 1) + scatter into ws ----------------
__global__ __launch_bounds__(256) void k_reduce2(const float* __restrict__ red,
                                                 float* __restrict__ ws) {
    const int f = blockIdx.x * 256 + threadIdx.x;
    if (f >= ENT) return;
    float sum = 0.0f;
#pragma unroll
    for (int pp = 0; pp < PSPLIT; ++pp) sum += red[(size_t)pp * ENT + f];
    const int s = f / PART_STRIDE, rest = f % PART_STRIDE;
    if (rest < SXX_FLOATS) {
        // rest = i*1024 + g*16 + j
        const int i = rest >> 10;
        const int g = (rest & 1023) >> 4;
        const int j = rest & 15;
        ws[SXX_OFF + (size_t)((s * NGROUP + g) * GD + i) * GD + j] = sum;
    } else {
        ws[SX_OFF + s * D_FEAT + (rest - SXX_FLOATS)] = sum;
    }
}

// ---------------- Pass 2: W = cov^{-1/2} via Newton-Schulz ----------------
// one block per (s,g); thread = (i = tid>>4, j = tid&15) entry of 16x16.
__global__ __launch_bounds__(256) void k_invsqrt(float* __restrict__ ws) {
    __shared__ float Ym[GD][GD];
    __shared__ float Zm[GD][GD];
    __shared__ float Tm[GD][GD];
    const int bx = blockIdx.x;
    const int s = bx / NGROUP, g = bx % NGROUP;
    const int tid = threadIdx.x;
    const int i = tid >> 4, j = tid & 15;
    const float invB = 1.0f / (float)NB;

    const float sxx = ws[SXX_OFF + (size_t)((s * NGROUP + g) * GD + i) * GD + j];
    const float mui = ws[SX_OFF + s * D_FEAT + g * GD + i] * invB;
    const float muj = ws[SX_OFF + s * D_FEAT + g * GD + j] * invB;
    const float a = sxx * invB - mui * muj;   // cov entry

    Ym[i][j] = a;
    __syncthreads();
    float tr = 0.0f;
#pragma unroll
    for (int k = 0; k < GD; ++k) tr += Ym[k][k];
    const float sc = tr * (1.0f / (float)GD);   // ~1.0 for N(0,1) data
    const float inv_sc = 1.0f / sc;
    __syncthreads();                            // all trace reads done
    Ym[i][j] = a * inv_sc;                      // normalized A, eig in ~[0.9,1.1]
    Zm[i][j] = (i == j) ? 1.0f : 0.0f;
    __syncthreads();

    float zn = (i == j) ? 1.0f : 0.0f;
    for (int it = 0; it < 6; ++it) {
        float t = 0.0f;
#pragma unroll
        for (int k = 0; k < GD; ++k) t += Zm[i][k] * Ym[k][j];
        t = ((i == j) ? 1.5f : 0.0f) - 0.5f * t;
        Tm[i][j] = t;
        __syncthreads();
        float yn = 0.0f;
        zn = 0.0f;
#pragma unroll
        for (int k = 0; k < GD; ++k) {
            yn += Ym[i][k] * Tm[k][j];
            zn += Tm[i][k] * Zm[k][j];
        }
        __syncthreads();
        Ym[i][j] = yn;
        Zm[i][j] = zn;
        __syncthreads();
    }
    // W = Z * sc^{-1/2}
    ws[W_OFF + (size_t)((s * NGROUP + g) * GD + i) * GD + j] = zn * rsqrtf(sc);
}

// ---------------- Pass 3: y = (x_gathered - mu) @ W, scattered back ----------------
// block: 256 threads; thread = (g = tid>>2, q = tid&3) owns W[:, q*4..q*4+3] in regs;
// gathers its quad from LDS, rebuilds v[16] via DPP, scatters u[4] to bout.
// (Exact R5 kernel — proven.)
__global__ __launch_bounds__(256, 3) void k_apply(const float* __restrict__ x,
                                                  const int* __restrict__ perms,
                                                  const float* __restrict__ ws,
                                                  float* __restrict__ out) {
    __shared__ float bin[2][C3][D_FEAT];             // 32 KB double-buffered input
    __shared__ float bout[C3][D_FEAT];               // 16 KB output staging
    const int s   = blockIdx.y;
    const int rb  = blockIdx.x;
    const int tid = threadIdx.x;
    const int g   = tid >> 2;
    const int q   = tid & 3;
    const float invB = 1.0f / (float)NB;

    int pcolq[4];
#pragma unroll
    for (int jj = 0; jj < 4; ++jj) pcolq[jj] = perms[s * D_FEAT + tid * 4 + jj];

    // W columns for this thread: w[e][ii] = W[s,g][e][q*4+ii]
    const float* Wp = ws + W_OFF + (size_t)(s * NGROUP + g) * GD * GD;
    float w[GD][4];
#pragma unroll
    for (int e = 0; e < GD; ++e) {
        float4 t4 = *(const float4*)&Wp[e * GD + q * 4];
        w[e][0] = t4.x; w[e][1] = t4.y; w[e][2] = t4.z; w[e][3] = t4.w;
    }
    // bias[ii] = sum_e mu[e] * w[e][ii]  (fold centering into the GEMV)
    float bias[4] = {0.0f, 0.0f, 0.0f, 0.0f};
#pragma unroll
    for (int e = 0; e < GD; ++e) {
        const float mu = ws[SX_OFF + s * D_FEAT + g * GD + e] * invB;
#pragma unroll
        for (int ii = 0; ii < 4; ++ii) bias[ii] += mu * w[e][ii];
    }

    const float* xbase = x + (size_t)(s * NB + rb * RPB3) * D_FEAT;
    float* obase = out + (size_t)(s * NB + rb * RPB3) * D_FEAT;
    constexpr int NCH = RPB3 / C3;                   // 8 chunks

    float4 rr[C3];
#pragma unroll
    for (int t = 0; t < C3; ++t)
        rr[t] = *(const float4*)&xbase[(size_t)t * D_FEAT + tid * 4];

    for (int k = 0; k < NCH; ++k) {
#pragma unroll
        for (int t = 0; t < C3; ++t)
            *(float4*)&bin[k & 1][t][tid * 4] = rr[t];
        __syncthreads();                             // bin[k&1] visible; bout(k-1) stores done
        if (k + 1 < NCH) {                           // prefetch under compute
            const float* nx = xbase + (size_t)(k + 1) * C3 * D_FEAT;
#pragma unroll
            for (int t = 0; t < C3; ++t)
                rr[t] = *(const float4*)&nx[(size_t)t * D_FEAT + tid * 4];
        }
        const float (*cb)[D_FEAT] = bin[k & 1];
#pragma unroll
        for (int r = 0; r < C3; ++r) {
            float vq[4];
#pragma unroll
            for (int jj = 0; jj < 4; ++jj) vq[jj] = cb[r][pcolq[jj]];
            float v[GD];
#pragma unroll
            for (int jj = 0; jj < 4; ++jj) {
                v[0  + jj] = qbc<0>(vq[jj]);
                v[4  + jj] = qbc<1>(vq[jj]);
                v[8  + jj] = qbc<2>(vq[jj]);
                v[12 + jj] = qbc<3>(vq[jj]);
            }
            float u[4] = {-bias[0], -bias[1], -bias[2], -bias[3]};
#pragma unroll
            for (int e = 0; e < GD; ++e)
#pragma unroll
                for (int ii = 0; ii < 4; ++ii) u[ii] = fmaf(v[e], w[e][ii], u[ii]);
#pragma unroll
            for (int ii = 0; ii < 4; ++ii) bout[r][pcolq[ii]] = u[ii];
        }
        __syncthreads();                             // bout complete
        float* ob = obase + (size_t)k * C3 * D_FEAT;
#pragma unroll
        for (int t = 0; t < C3; ++t)
            *(float4*)&ob[(size_t)t * D_FEAT + tid * 4] =
                *(const float4*)&bout[t][tid * 4];
    }
}

extern "C" void kernel_launch(void* const* d_in, const int* in_sizes, int n_in,
                              void* d_out, int out_size, void* d_ws, size_t ws_size,
                              hipStream_t stream) {
    const float* x     = (const float*)d_in[0];
    const int*   perms = (const int*)d_in[1];
    float* out = (float*)d_out;
    float* ws  = (float*)d_ws;

    // Partials (3*256*17408 floats = 53.5 MB) live in d_out: it is 100 MB and
    // k_apply fully overwrites every element afterwards. ws only needs 2.1 MB.
    float* part = out;

    dim3 g1(P1, NVIEW);                              // 768 blocks = 3/CU
    k_stats_gather<<<g1, 256, 0, stream>>>(x, perms, part);

    dim3 gr1((ENT + 255) / 256, PSPLIT);             // (204, 8)
    k_reduce1<<<gr1, 256, 0, stream>>>(part, ws + RED_OFF);
    k_reduce2<<<(ENT + 255) / 256, 256, 0, stream>>>(ws + RED_OFF, ws);

    k_invsqrt<<<NVIEW * NGROUP, 256, 0, stream>>>(ws);

    dim3 g3(NB / RPB3, NVIEW);                       // 768 blocks = 3/CU
    k_apply<<<g3, 256, 0, stream>>>(x, perms, ws, out);
}